// Round 1
// baseline (11914.943 us; speedup 1.0000x reference)
//
#include <hip/hip_runtime.h>
#include <stdint.h>
#include <math.h>

// Bayesian STDP persistent-scan kernel, v5: tag-validated stats exchange.
// vs v4: the grid flag-barrier is REMOVED. Each (mx,ssum) stats entry is
// self-validating: epoch parity ((t>>1)&1) is encoded in the sign of ssum
// (|ssum| >= 1 always, so 0x00- and 0xAA-poisoned workspace both read as
// invalid). The 8-byte relaxed atomic carries data+tag together, so no
// fences, no vmcnt drains, no flag round trip. The psp recurrence (F) is
// moved BETWEEN the stats post and the stats poll so its ~1us of LDS work
// hides the cross-XCD propagation latency. Phase D's strided psp reads are
// preloaded into registers during phase A, taking the 4-way-bank-conflict
// loads off the critical dependence chain.

#define TSTEPS 1000
#define BB     64
#define NINF   512
#define NOUTT  128
#define NG     32
#define NO     4
#define NTHR   1024
#define PSPD   0.9f
#define VD     0.9f
#define LRC    1e-3f
#define PS     516                  // padded row stride (floats), 16B-multiple

__device__ __forceinline__ void sync_lds() {
  // barrier draining only LDS (lgkmcnt=0, vmcnt=63, expcnt=7)
  asm volatile("" ::: "memory");
  __builtin_amdgcn_s_waitcnt(0xC07F);
  __builtin_amdgcn_s_barrier();
  asm volatile("" ::: "memory");
}

__device__ __forceinline__ float2 aload_f2(const float* p) {
  unsigned long long u = __hip_atomic_load((const unsigned long long*)p,
      __ATOMIC_RELAXED, __HIP_MEMORY_SCOPE_AGENT);
  float2 r;
  r.x = __uint_as_float((unsigned)u);
  r.y = __uint_as_float((unsigned)(u >> 32));
  return r;
}
__device__ __forceinline__ void astore_f2(float* p, float x, float y) {
  unsigned long long u = (unsigned long long)__float_as_uint(x)
                       | ((unsigned long long)__float_as_uint(y) << 32);
  __hip_atomic_store((unsigned long long*)p, u, __ATOMIC_RELAXED, __HIP_MEMORY_SCOPE_AGENT);
}

__global__ __launch_bounds__(NTHR)
void bstdp_kernel(const float* __restrict__ spikes,   // [T][B][NIN]
                  const float* __restrict__ weight,   // [NOUT][NIN]
                  const float* __restrict__ bias,     // [NOUT]
                  float* __restrict__ out,            // [T][B][NOUT] ++ [B][NOUT]
                  float* __restrict__ ws)
{
  const int g   = blockIdx.x;
  const int tid = threadIdx.x;

  float* stats = ws;                       // [2][NG][BB][2] floats (tag in sign of ssum)

  __shared__ __align__(16) float psp[BB*PS];   // 132 KB replicated psp trace
  __shared__ __align__(16) float Wt[NO*PS];    // 8.25 KB W tile (padded rows)
  __shared__ __align__(16) float zT[296];      // swizzled z [b][o]
  __shared__ __align__(16) float uS[NO*BB];    // membrane [o][b]
  __shared__ float pmS[16];                    // per-wave pm partials [w][o]
  __shared__ float btS[NO];

  // ---- prologue: W tile, bias, u=0, psp(0) = spikes(0) ----
  #pragma unroll
  for (int e = tid; e < NO*NINF; e += NTHR)
    Wt[(e>>9)*PS + (e&511)] = weight[g*(NO*NINF) + e];
  if (tid < NO)    btS[tid] = bias[g*NO + tid];
  if (tid < NO*BB) uS[tid] = 0.0f;
  #pragma unroll
  for (int k = 0; k < 8; ++k) {
    int j = tid*4 + k*4096;
    *(float4*)&psp[(j>>9)*PS + (j&511)] = *(const float4*)(spikes + j);
  }
  __syncthreads();

  const int bp = tid >> 5, cc = tid & 31;     // GEMM1: rows (bp, bp+32), chunk cc
  const int q4 = tid & 3,  b4 = tid >> 2;     // phase C (tid<256)
  const int dbh = tid & 3;                    // phase D: batch quarter
  const int di  = (tid >> 2) * 2;             // phase D: column pair

  for (int t = 0; t < TSTEPS; ++t) {
    const int sb = t & 1;
    const float sgn = ((t >> 1) & 1) ? -1.0f : 1.0f;   // epoch parity tag

    // ---------- A: spikes(t+1) prefetch + GEMM1 from LDS ----------
    float4 spn[8];
    if (t + 1 < TSTEPS) {
      const float* sp = spikes + (size_t)(t+1)*(BB*NINF) + tid*4;
      #pragma unroll
      for (int k = 0; k < 8; ++k) spn[k] = *(const float4*)(sp + k*4096);
    }
    {
      float a0[NO] = {0.f,0.f,0.f,0.f};
      float a1[NO] = {0.f,0.f,0.f,0.f};
      const float* pr0 = &psp[bp*PS];
      const float* pr1 = &psp[(bp+32)*PS];
      #pragma unroll
      for (int k = 0; k < 4; ++k) {
        float4 p0 = *(const float4*)(pr0 + cc*4 + k*128);
        float4 p1 = *(const float4*)(pr1 + cc*4 + k*128);
        #pragma unroll
        for (int o = 0; o < NO; ++o) {
          float4 w = *(const float4*)(&Wt[o*PS + cc*4 + k*128]);
          a0[o] = fmaf(p0.x,w.x, fmaf(p0.y,w.y, fmaf(p0.z,w.z, fmaf(p0.w,w.w, a0[o]))));
          a1[o] = fmaf(p1.x,w.x, fmaf(p1.y,w.y, fmaf(p1.z,w.z, fmaf(p1.w,w.w, a1[o]))));
        }
      }
      #pragma unroll
      for (int m = 1; m < 32; m <<= 1) {
        #pragma unroll
        for (int o = 0; o < NO; ++o) {
          a0[o] += __shfl_xor(a0[o], m);
          a1[o] += __shfl_xor(a1[o], m);
        }
      }
      if (cc == 0) {
        #pragma unroll
        for (int o = 0; o < NO; ++o) {
          uS[o*BB + bp]      = VD*uS[o*BB + bp]      + a0[o] + btS[o];
          uS[o*BB + bp + 32] = VD*uS[o*BB + bp + 32] + a1[o] + btS[o];
        }
      }
    }
    // ---------- Apre: preload phase-D psp slice into registers ----------
    float2 pv[16];
    #pragma unroll
    for (int r = 0; r < 16; ++r)
      pv[r] = *(const float2*)&psp[(dbh*16 + r)*PS + di];

    sync_lds();   // uS visible; all psp(t) reads complete

    // ---------- B: post tagged softmax stats (no fence, no flag) ----------
    if (tid < BB) {
      float u0 = uS[0*BB+tid], u1 = uS[1*BB+tid], u2 = uS[2*BB+tid], u3 = uS[3*BB+tid];
      float mx = fmaxf(fmaxf(u0,u1), fmaxf(u2,u3));
      float ssum = expf(u0-mx)+expf(u1-mx)+expf(u2-mx)+expf(u3-mx);  // in [1,4]
      astore_f2(stats + ((size_t)(sb*NG + g)*BB + tid)*2, mx, ssum*sgn);
    }

    // ---------- F: psp recurrence — hides cross-XCD stats propagation ----------
    if (t + 1 < TSTEPS) {
      #pragma unroll
      for (int k = 0; k < 8; ++k) {
        int j = tid*4 + k*4096;
        float* pa = &psp[(j>>9)*PS + (j&511)];
        float4 p = *(float4*)pa;
        p.x = PSPD*p.x + spn[k].x;
        p.y = PSPD*p.y + spn[k].y;
        p.z = PSPD*p.z + spn[k].z;
        p.w = PSPD*p.w + spn[k].w;
        *(float4*)pa = p;
      }
    }

    // ---------- C: poll tagged stats, merge, z, out store, pm partials ----------
    if (tid < 256) {
      float2 msv[8];
      #pragma unroll
      for (int k = 0; k < 8; ++k)
        msv[k] = aload_f2(stats + ((size_t)(sb*NG + (q4*8 + k))*BB + b4)*2);
      for (;;) {
        int bad = 0;
        #pragma unroll
        for (int k = 0; k < 8; ++k)
          bad |= (msv[k].y * sgn >= 1.0f) ? 0 : (1 << k);   // valid iff tagged this epoch
        if (!bad) break;
        __builtin_amdgcn_s_sleep(1);
        #pragma unroll
        for (int k = 0; k < 8; ++k)
          if (bad & (1 << k))
            msv[k] = aload_f2(stats + ((size_t)(sb*NG + (q4*8 + k))*BB + b4)*2);
      }
      float M = -1e30f, S = 0.f;
      #pragma unroll
      for (int k = 0; k < 8; ++k) {
        float mxv = msv[k].x, sv = fabsf(msv[k].y);
        float Mn = fmaxf(M, mxv);
        S = S*expf(M - Mn) + sv*expf(mxv - Mn);
        M = Mn;
      }
      #pragma unroll
      for (int m = 1; m < 4; m <<= 1) {
        float Mo = __shfl_xor(M, m);
        float So = __shfl_xor(S, m);
        float Mn = fmaxf(M, Mo);
        S = S*expf(M - Mn) + So*expf(Mo - Mn);
        M = Mn;
      }
      float z = expf(uS[q4*BB + b4] - M) / S;
      zT[b4*4 + q4 + 4*(b4>>3)] = z;               // swizzled for phase D
      __builtin_nontemporal_store(z,
          out + (size_t)t*(BB*NOUTT) + (size_t)b4*NOUTT + g*NO + q4);
      float v = z;
      #pragma unroll
      for (int m = 4; m < 64; m <<= 1) v += __shfl_xor(v, m);
      if ((tid & 63) < 4) pmS[(tid >> 6)*NO + q4] = v;
    }
    sync_lds();   // zT, pmS visible; psp(t+1) complete

    // ---------- D/E: post_pre from registers + W,b update ----------
    if (t + 1 < TSTEPS) {
      float pp[NO][2] = {};
      #pragma unroll
      for (int r = 0; r < 16; ++r) {
        int b = dbh*16 + r;
        float2 pvl = pv[r];
        float4 z4 = *(const float4*)&zT[b*4 + 4*(b>>3)];
        pp[0][0] = fmaf(z4.x, pvl.x, pp[0][0]); pp[0][1] = fmaf(z4.x, pvl.y, pp[0][1]);
        pp[1][0] = fmaf(z4.y, pvl.x, pp[1][0]); pp[1][1] = fmaf(z4.y, pvl.y, pp[1][1]);
        pp[2][0] = fmaf(z4.z, pvl.x, pp[2][0]); pp[2][1] = fmaf(z4.z, pvl.y, pp[2][1]);
        pp[3][0] = fmaf(z4.w, pvl.x, pp[3][0]); pp[3][1] = fmaf(z4.w, pvl.y, pp[3][1]);
      }
      // combine the 4 batch-quarters (lanes differing in tid&3)
      #pragma unroll
      for (int m = 1; m < 4; m <<= 1) {
        #pragma unroll
        for (int o = 0; o < NO; ++o) {
          pp[o][0] += __shfl_xor(pp[o][0], m);
          pp[o][1] += __shfl_xor(pp[o][1], m);
        }
      }
      // lane with dbh==o updates W[o][di], W[o][di+1]
      float ppx, ppy;
      switch (dbh) {
        case 0: ppx = pp[0][0]; ppy = pp[0][1]; break;
        case 1: ppx = pp[1][0]; ppy = pp[1][1]; break;
        case 2: ppx = pp[2][0]; ppy = pp[2][1]; break;
        default: ppx = pp[3][0]; ppy = pp[3][1]; break;
      }
      float pm = (pmS[dbh] + pmS[NO+dbh] + pmS[2*NO+dbh] + pmS[3*NO+dbh]) * (1.0f/BB);
      float* wp = &Wt[dbh*PS + di];
      float w0 = wp[0], w1 = wp[1];
      wp[0] = w0 + LRC*(expf(-w0)*ppx*(1.0f/BB) - pm);
      wp[1] = w1 + LRC*(expf(-w1)*ppy*(1.0f/BB) - pm);
      if (tid < NO) {
        float pmb = (pmS[tid] + pmS[NO+tid] + pmS[2*NO+tid] + pmS[3*NO+tid]) * (1.0f/BB);
        float bv = btS[tid];
        btS[tid] = bv + LRC*(expf(-bv) - 1.0f)*pmb;
      }
    }
    sync_lds();   // Wt/btS visible for next A; zT free for next C
  }

  // ---- epilogue: u_final ----
  if (tid < 256) {
    __builtin_nontemporal_store(uS[q4*BB + b4],
        out + (size_t)TSTEPS*(BB*NOUTT) + (size_t)b4*NOUTT + g*NO + q4);
  }
}

extern "C" void kernel_launch(void* const* d_in, const int* in_sizes, int n_in,
                              void* d_out, int out_size, void* d_ws, size_t ws_size,
                              hipStream_t stream) {
  const float* spikes = (const float*)d_in[0];   // [1000,64,512] fp32
  const float* weight = (const float*)d_in[1];   // [128,512] fp32
  const float* bias   = (const float*)d_in[2];   // [128] fp32
  float* out = (float*)d_out;                    // [1000*64*128] ++ [64*128]
  float* ws  = (float*)d_ws;

  bstdp_kernel<<<dim3(NG), dim3(NTHR), 0, stream>>>(spikes, weight, bias, out, ws);
}

// Round 2
// 10188.805 us; speedup vs baseline: 1.1694x; 1.1694x over previous
//
#include <hip/hip_runtime.h>
#include <stdint.h>
#include <math.h>

// Bayesian STDP persistent-scan kernel, v6: LDS-pipe diet.
// vs v5: (1) GEMM1 restructured — each wave owns 4 batch rows, lane owns 8
// columns; 16 ds_read_b128/thread (was 24) and a 17-op value-folding
// butterfly reduction (was 40 shfl). (2) Apre preload dropped; phase D reads
// psp directly with a per-dbh row rotation that makes the reads bank-conflict
// free (shifts {0,8,16,24} across the 4 colliding lanes). (3) Step order:
// A -> B -> C -> D/E -> F with 4 LDS-only barriers. Exchange stays the
// tag-validated relaxed-atomic scheme (sign of ssum = epoch parity).

#define TSTEPS 1000
#define BB     64
#define NINF   512
#define NOUTT  128
#define NG     32
#define NO     4
#define NTHR   1024
#define PSPD   0.9f
#define VD     0.9f
#define LRC    1e-3f
#define PS     516                  // padded row stride (floats), 16B-multiple

__device__ __forceinline__ void sync_lds() {
  // barrier draining only LDS (lgkmcnt=0, vmcnt=63, expcnt=7)
  asm volatile("" ::: "memory");
  __builtin_amdgcn_s_waitcnt(0xC07F);
  __builtin_amdgcn_s_barrier();
  asm volatile("" ::: "memory");
}

__device__ __forceinline__ float2 aload_f2(const float* p) {
  unsigned long long u = __hip_atomic_load((const unsigned long long*)p,
      __ATOMIC_RELAXED, __HIP_MEMORY_SCOPE_AGENT);
  float2 r;
  r.x = __uint_as_float((unsigned)u);
  r.y = __uint_as_float((unsigned)(u >> 32));
  return r;
}
__device__ __forceinline__ void astore_f2(float* p, float x, float y) {
  unsigned long long u = (unsigned long long)__float_as_uint(x)
                       | ((unsigned long long)__float_as_uint(y) << 32);
  __hip_atomic_store((unsigned long long*)p, u, __ATOMIC_RELAXED, __HIP_MEMORY_SCOPE_AGENT);
}

__global__ __launch_bounds__(NTHR)
void bstdp_kernel(const float* __restrict__ spikes,   // [T][B][NIN]
                  const float* __restrict__ weight,   // [NOUT][NIN]
                  const float* __restrict__ bias,     // [NOUT]
                  float* __restrict__ out,            // [T][B][NOUT] ++ [B][NOUT]
                  float* __restrict__ ws)
{
  const int g   = blockIdx.x;
  const int tid = threadIdx.x;

  float* stats = ws;                       // [2][NG][BB][2] floats (tag in sign of ssum)

  __shared__ __align__(16) float psp[BB*PS];   // 132 KB replicated psp trace
  __shared__ __align__(16) float Wt[NO*PS];    // 8.25 KB W tile (padded rows)
  __shared__ __align__(16) float zT[296];      // swizzled z [b][o]
  __shared__ __align__(16) float uS[NO*BB];    // membrane [o][b]
  __shared__ float pmS[16];                    // per-wave pm partials [w][o]
  __shared__ float btS[NO];

  // ---- prologue: W tile, bias, u=0, psp(0) = spikes(0) ----
  #pragma unroll
  for (int e = tid; e < NO*NINF; e += NTHR)
    Wt[(e>>9)*PS + (e&511)] = weight[g*(NO*NINF) + e];
  if (tid < NO)    btS[tid] = bias[g*NO + tid];
  if (tid < NO*BB) uS[tid] = 0.0f;
  #pragma unroll
  for (int k = 0; k < 8; ++k) {
    int j = tid*4 + k*4096;
    *(float4*)&psp[(j>>9)*PS + (j&511)] = *(const float4*)(spikes + j);
  }
  __syncthreads();

  const int w  = tid >> 6;                    // wave 0..15 (owns batch rows w*4..w*4+3)
  const int ln = tid & 63;
  const int c0 = (ln & 31) * 4 + (ln >> 5) * 128;   // GEMM1 column base (bank-uniform)
  const int q4 = tid & 3,  b4 = tid >> 2;     // phase C (tid<256)
  const int dbh = tid & 3;                    // phase D: batch quarter
  const int di  = (tid >> 2) * 2;             // phase D: column pair

  for (int t = 0; t < TSTEPS; ++t) {
    const int sb = t & 1;
    const float sgn = ((t >> 1) & 1) ? -1.0f : 1.0f;   // epoch parity tag

    // ---------- A: spikes(t+1) prefetch + GEMM1 (wave-owns-4-rows) ----------
    float4 spn[8];
    if (t + 1 < TSTEPS) {
      const float* sp = spikes + (size_t)(t+1)*(BB*NINF) + tid*4;
      #pragma unroll
      for (int k = 0; k < 8; ++k) spn[k] = *(const float4*)(sp + k*4096);
    }
    {
      float acc[16];
      #pragma unroll
      for (int i = 0; i < 16; ++i) acc[i] = 0.0f;
      #pragma unroll
      for (int k = 0; k < 2; ++k) {
        const int cb = c0 + k*256;
        float4 p[4], wv[4];
        #pragma unroll
        for (int r = 0; r < 4; ++r) p[r]  = *(const float4*)&psp[(w*4+r)*PS + cb];
        #pragma unroll
        for (int o = 0; o < 4; ++o) wv[o] = *(const float4*)&Wt[o*PS + cb];
        #pragma unroll
        for (int r = 0; r < 4; ++r) {
          #pragma unroll
          for (int o = 0; o < 4; ++o) {
            acc[r*4+o] = fmaf(p[r].x, wv[o].x, fmaf(p[r].y, wv[o].y,
                         fmaf(p[r].z, wv[o].z, fmaf(p[r].w, wv[o].w, acc[r*4+o]))));
          }
        }
      }
      // value-folding butterfly: lane ln ends with full sum of acc[ln&15]
      #pragma unroll
      for (int j = 0; j < 8; ++j) {             // xor1: 16 -> 8
        float s_ = (ln & 1) ? acc[2*j]   : acc[2*j+1];
        float k_ = (ln & 1) ? acc[2*j+1] : acc[2*j];
        acc[j] = k_ + __shfl_xor(s_, 1);
      }
      #pragma unroll
      for (int j = 0; j < 4; ++j) {             // xor2: 8 -> 4
        float s_ = (ln & 2) ? acc[2*j]   : acc[2*j+1];
        float k_ = (ln & 2) ? acc[2*j+1] : acc[2*j];
        acc[j] = k_ + __shfl_xor(s_, 2);
      }
      #pragma unroll
      for (int j = 0; j < 2; ++j) {             // xor4: 4 -> 2
        float s_ = (ln & 4) ? acc[2*j]   : acc[2*j+1];
        float k_ = (ln & 4) ? acc[2*j+1] : acc[2*j];
        acc[j] = k_ + __shfl_xor(s_, 4);
      }
      {                                          // xor8: 2 -> 1
        float s_ = (ln & 8) ? acc[0] : acc[1];
        float k_ = (ln & 8) ? acc[1] : acc[0];
        acc[0] = k_ + __shfl_xor(s_, 8);
      }
      acc[0] += __shfl_xor(acc[0], 16);
      acc[0] += __shfl_xor(acc[0], 32);
      if (ln < 16) {
        const int o = ln & 3, r = ln >> 2;
        const int row = w*4 + r;
        uS[o*BB + row] = VD*uS[o*BB + row] + acc[0] + btS[o];
      }
    }
    sync_lds();   // uS complete

    // ---------- B: post tagged softmax stats (no fence, no flag) ----------
    if (tid < BB) {
      float u0 = uS[0*BB+tid], u1 = uS[1*BB+tid], u2 = uS[2*BB+tid], u3 = uS[3*BB+tid];
      float mx = fmaxf(fmaxf(u0,u1), fmaxf(u2,u3));
      float ssum = expf(u0-mx)+expf(u1-mx)+expf(u2-mx)+expf(u3-mx);  // in [1,4]
      astore_f2(stats + ((size_t)(sb*NG + g)*BB + tid)*2, mx, ssum*sgn);
    }

    // ---------- C: poll tagged stats, merge, z, out store, pm partials ----------
    if (tid < 256) {
      float2 msv[8];
      #pragma unroll
      for (int k = 0; k < 8; ++k)
        msv[k] = aload_f2(stats + ((size_t)(sb*NG + (q4*8 + k))*BB + b4)*2);
      for (;;) {
        int bad = 0;
        #pragma unroll
        for (int k = 0; k < 8; ++k)
          bad |= (msv[k].y * sgn >= 1.0f) ? 0 : (1 << k);   // valid iff tagged this epoch
        if (!bad) break;
        __builtin_amdgcn_s_sleep(1);
        #pragma unroll
        for (int k = 0; k < 8; ++k)
          if (bad & (1 << k))
            msv[k] = aload_f2(stats + ((size_t)(sb*NG + (q4*8 + k))*BB + b4)*2);
      }
      float M = -1e30f, S = 0.f;
      #pragma unroll
      for (int k = 0; k < 8; ++k) {
        float mxv = msv[k].x, sv = fabsf(msv[k].y);
        float Mn = fmaxf(M, mxv);
        S = S*expf(M - Mn) + sv*expf(mxv - Mn);
        M = Mn;
      }
      #pragma unroll
      for (int m = 1; m < 4; m <<= 1) {
        float Mo = __shfl_xor(M, m);
        float So = __shfl_xor(S, m);
        float Mn = fmaxf(M, Mo);
        S = S*expf(M - Mn) + So*expf(Mo - Mn);
        M = Mn;
      }
      float z = expf(uS[q4*BB + b4] - M) / S;
      zT[b4*4 + q4 + 4*(b4>>3)] = z;               // swizzled for phase D
      __builtin_nontemporal_store(z,
          out + (size_t)t*(BB*NOUTT) + (size_t)b4*NOUTT + g*NO + q4);
      float v = z;
      #pragma unroll
      for (int m = 4; m < 64; m <<= 1) v += __shfl_xor(v, m);
      if ((tid & 63) < 4) pmS[(tid >> 6)*NO + q4] = v;
    }
    sync_lds();   // zT, pmS visible

    // ---------- D/E: post_pre (rotated, conflict-free psp reads) + W,b update ----------
    if (t + 1 < TSTEPS) {
      float pp[NO][2] = {};
      #pragma unroll
      for (int i = 0; i < 16; ++i) {
        int b = dbh*16 + ((i + 2*dbh) & 15);      // rotation: bank shifts {0,8,16,24}
        float2 pvl = *(const float2*)&psp[b*PS + di];
        float4 z4 = *(const float4*)&zT[b*4 + 4*(b>>3)];
        pp[0][0] = fmaf(z4.x, pvl.x, pp[0][0]); pp[0][1] = fmaf(z4.x, pvl.y, pp[0][1]);
        pp[1][0] = fmaf(z4.y, pvl.x, pp[1][0]); pp[1][1] = fmaf(z4.y, pvl.y, pp[1][1]);
        pp[2][0] = fmaf(z4.z, pvl.x, pp[2][0]); pp[2][1] = fmaf(z4.z, pvl.y, pp[2][1]);
        pp[3][0] = fmaf(z4.w, pvl.x, pp[3][0]); pp[3][1] = fmaf(z4.w, pvl.y, pp[3][1]);
      }
      // combine the 4 batch-quarters (lanes differing in tid&3)
      #pragma unroll
      for (int m = 1; m < 4; m <<= 1) {
        #pragma unroll
        for (int o = 0; o < NO; ++o) {
          pp[o][0] += __shfl_xor(pp[o][0], m);
          pp[o][1] += __shfl_xor(pp[o][1], m);
        }
      }
      // lane with dbh==o updates W[o][di], W[o][di+1]
      float ppx, ppy;
      switch (dbh) {
        case 0: ppx = pp[0][0]; ppy = pp[0][1]; break;
        case 1: ppx = pp[1][0]; ppy = pp[1][1]; break;
        case 2: ppx = pp[2][0]; ppy = pp[2][1]; break;
        default: ppx = pp[3][0]; ppy = pp[3][1]; break;
      }
      float pm = (pmS[dbh] + pmS[NO+dbh] + pmS[2*NO+dbh] + pmS[3*NO+dbh]) * (1.0f/BB);
      float* wp = &Wt[dbh*PS + di];
      float w0 = wp[0], w1 = wp[1];
      wp[0] = w0 + LRC*(expf(-w0)*ppx*(1.0f/BB) - pm);
      wp[1] = w1 + LRC*(expf(-w1)*ppy*(1.0f/BB) - pm);
      if (tid < NO) {
        float pmb = (pmS[tid] + pmS[NO+tid] + pmS[2*NO+tid] + pmS[3*NO+tid]) * (1.0f/BB);
        float bv = btS[tid];
        btS[tid] = bv + LRC*(expf(-bv) - 1.0f)*pmb;
      }
    }
    sync_lds();   // all psp(t) reads done; Wt/btS updated

    // ---------- F: psp recurrence (in-place, LDS-local) ----------
    if (t + 1 < TSTEPS) {
      #pragma unroll
      for (int k = 0; k < 8; ++k) {
        int j = tid*4 + k*4096;
        float* pa = &psp[(j>>9)*PS + (j&511)];
        float4 p = *(float4*)pa;
        p.x = PSPD*p.x + spn[k].x;
        p.y = PSPD*p.y + spn[k].y;
        p.z = PSPD*p.z + spn[k].z;
        p.w = PSPD*p.w + spn[k].w;
        *(float4*)pa = p;
      }
    }
    sync_lds();   // psp(t+1) ready for next A
  }

  // ---- epilogue: u_final ----
  if (tid < 256) {
    __builtin_nontemporal_store(uS[q4*BB + b4],
        out + (size_t)TSTEPS*(BB*NOUTT) + (size_t)b4*NOUTT + g*NO + q4);
  }
}

extern "C" void kernel_launch(void* const* d_in, const int* in_sizes, int n_in,
                              void* d_out, int out_size, void* d_ws, size_t ws_size,
                              hipStream_t stream) {
  const float* spikes = (const float*)d_in[0];   // [1000,64,512] fp32
  const float* weight = (const float*)d_in[1];   // [128,512] fp32
  const float* bias   = (const float*)d_in[2];   // [128] fp32
  float* out = (float*)d_out;                    // [1000*64*128] ++ [64*128]
  float* ws  = (float*)d_ws;

  bstdp_kernel<<<dim3(NG), dim3(NTHR), 0, stream>>>(spikes, weight, bias, out, ws);
}